// Round 1
// baseline (3895.576 us; speedup 1.0000x reference)
//
#include <hip/hip_runtime.h>

// Problem constants
#define S2q 32
#define Bq  32
#define CIq 64
#define COq 64
#define Lq  256
#define Kq  3
#define Aq  16
#define Hq  128
#define EPSq 1e-5f

// LT = 8 l-values per block, OC = 8 output channels per chunk (8 chunks)
#define LT 8
#define OC 8

// ---------------------------------------------------------------------------
// Kernel 1: hypernets. One block per (b,l). Computes
//   hv[b,l,128]  = relu(LN(z@W1+b1))          -> ws
//   bias[b,l,64] = relu(LN(z@Wb1+bb1)) @ Wb2 + bb2 -> ws
// ---------------------------------------------------------------------------
__global__ __launch_bounds__(128) void hyper_kernel(
    const float* __restrict__ z,
    const float* __restrict__ W1,  const float* __restrict__ b1,
    const float* __restrict__ g1,  const float* __restrict__ be1,
    const float* __restrict__ Wb1, const float* __restrict__ bb1,
    const float* __restrict__ gb1, const float* __restrict__ beb1,
    const float* __restrict__ Wb2, const float* __restrict__ bb2,
    float* __restrict__ hv_ws, float* __restrict__ bias_ws)
{
    const int bl = blockIdx.x;      // b*256 + l
    const int j  = threadIdx.x;     // 0..127 (h index)

    __shared__ float zs[Aq];
    __shared__ float r1[Hq];
    __shared__ float r2[Hq];
    __shared__ float hbs[Hq];

    if (j < Aq) zs[j] = z[bl * Aq + j];
    __syncthreads();

    // ---- weight hypernet first layer + LN + relu ----
    float pre = b1[j];
    #pragma unroll
    for (int a = 0; a < Aq; ++a) pre += zs[a] * W1[a * Hq + j];

    r1[j] = pre; r2[j] = pre * pre;
    __syncthreads();
    for (int off = 64; off > 0; off >>= 1) {
        if (j < off) { r1[j] += r1[j + off]; r2[j] += r2[j + off]; }
        __syncthreads();
    }
    float mu  = r1[0] * (1.0f / 128.0f);
    float var = r2[0] * (1.0f / 128.0f) - mu * mu;
    float hval = (pre - mu) * rsqrtf(var + EPSq) * g1[j] + be1[j];
    hval = hval > 0.0f ? hval : 0.0f;
    hv_ws[bl * Hq + j] = hval;

    // ---- bias hypernet first layer + LN + relu ----
    float preb = bb1[j];
    #pragma unroll
    for (int a = 0; a < Aq; ++a) preb += zs[a] * Wb1[a * Hq + j];

    __syncthreads();   // r1/r2 reuse
    r1[j] = preb; r2[j] = preb * preb;
    __syncthreads();
    for (int off = 64; off > 0; off >>= 1) {
        if (j < off) { r1[j] += r1[j + off]; r2[j] += r2[j + off]; }
        __syncthreads();
    }
    float mub  = r1[0] * (1.0f / 128.0f);
    float varb = r2[0] * (1.0f / 128.0f) - mub * mub;
    float hbv = (preb - mub) * rsqrtf(varb + EPSq) * gb1[j] + beb1[j];
    hbv = hbv > 0.0f ? hbv : 0.0f;
    hbs[j] = hbv;
    __syncthreads();

    // ---- bias second linear: 64 outputs ----
    if (j < COq) {
        float acc = bb2[j];
        #pragma unroll 8
        for (int h = 0; h < Hq; ++h) acc += hbs[h] * Wb2[h * COq + j];
        bias_ws[bl * COq + j] = acc;
    }
}

// ---------------------------------------------------------------------------
// Kernel 2: fused weight-gen (GEMM1) + conv.
// grid = (32 l-tiles, 32 b), 256 threads.
// Per o-chunk (8 o's): compute w[8l][64i][3k][8oo] in LDS, then conv.
// ---------------------------------------------------------------------------
__global__ __launch_bounds__(256) void fused_kernel(
    const float* __restrict__ x,
    const float* __restrict__ W2, const float* __restrict__ b2,
    const float* __restrict__ hv_ws, const float* __restrict__ bias_ws,
    float* __restrict__ out)
{
    const int b    = blockIdx.y;           // 0..31
    const int tile = blockIdx.x;           // 0..31
    const int l0   = tile * LT;
    const int tid  = threadIdx.x;

    __shared__ float hv[LT * Hq];          // 4 KB
    __shared__ float wl[LT * 1536];        // 48 KB : [l][ (i*3+k)*8 + oo ]

    // stage hv rows l0..l0+7 (contiguous 1024 floats)
    for (int v = tid; v < LT * Hq; v += 256)
        hv[v] = hv_ws[(b * Lq + l0) * Hq + v];

    const int s  = tid & 31;               // conv: s index
    const int og = tid >> 5;               // conv: which oo within chunk

    const float* xrow = x + ((size_t)(s * Bq + b) * CIq) * Lq;

    for (int oc = 0; oc < 8; ++oc) {
        const int o0 = oc * OC;
        __syncthreads();  // wl safe to overwrite

        // ---- GEMM1: 1536 cols for this o-chunk ----
        float acc[6][LT];
        int   cidx[6];
        #pragma unroll
        for (int jj = 0; jj < 6; ++jj) {
            int cc = tid + 256 * jj;       // 0..1535
            int oo = cc & 7;
            int t  = cc >> 3;              // i*3 + k, 0..191
            int i  = t / 3;
            int k  = t - 3 * i;
            cidx[jj] = i * 192 + (o0 + oo) * 3 + k;   // W2 column
            #pragma unroll
            for (int l = 0; l < LT; ++l) acc[jj][l] = 0.0f;
        }
        #pragma unroll 4
        for (int h = 0; h < Hq; ++h) {
            float wv[6];
            #pragma unroll
            for (int jj = 0; jj < 6; ++jj) wv[jj] = W2[h * 12288 + cidx[jj]];
            #pragma unroll
            for (int l = 0; l < LT; ++l) {
                float hvv = hv[l * Hq + h];
                #pragma unroll
                for (int jj = 0; jj < 6; ++jj) acc[jj][l] += hvv * wv[jj];
            }
        }
        #pragma unroll
        for (int jj = 0; jj < 6; ++jj) {
            float bb = b2[cidx[jj]];
            int cc = tid + 256 * jj;
            #pragma unroll
            for (int l = 0; l < LT; ++l) wl[l * 1536 + cc] = acc[jj][l] + bb;
        }
        __syncthreads();

        // ---- conv for o = o0 + og, all 8 l's, fixed s ----
        float cacc[LT];
        #pragma unroll
        for (int l = 0; l < LT; ++l) cacc[l] = 0.0f;

        for (int i = 0; i < CIq; ++i) {
            float xr[LT + 3];  // x[s,b,i, l0-1 .. l0+9]
            #pragma unroll
            for (int q = 0; q < LT + 3; ++q) {
                int ll = l0 - 1 + q;
                xr[q] = (ll >= 0 && ll < Lq) ? xrow[i * Lq + ll] : 0.0f;
            }
            #pragma unroll
            for (int l = 0; l < LT; ++l) {
                #pragma unroll
                for (int k = 0; k < Kq; ++k) {
                    cacc[l] += xr[l + k] * wl[l * 1536 + (i * 3 + k) * 8 + og];
                }
            }
        }

        const int o = o0 + og;
        #pragma unroll
        for (int l = 0; l < LT; ++l) {
            float bv = bias_ws[(b * Lq + l0 + l) * COq + o];
            out[((size_t)(s * Bq + b) * COq + o) * Lq + l0 + l] = cacc[l] + bv;
        }
    }
}

// ---------------------------------------------------------------------------
extern "C" void kernel_launch(void* const* d_in, const int* in_sizes, int n_in,
                              void* d_out, int out_size, void* d_ws, size_t ws_size,
                              hipStream_t stream) {
    const float* x    = (const float*)d_in[0];
    const float* z    = (const float*)d_in[1];
    const float* W1   = (const float*)d_in[2];
    const float* b1   = (const float*)d_in[3];
    const float* g1   = (const float*)d_in[4];
    const float* be1  = (const float*)d_in[5];
    const float* W2   = (const float*)d_in[6];
    const float* b2   = (const float*)d_in[7];
    const float* Wb1  = (const float*)d_in[8];
    const float* bb1  = (const float*)d_in[9];
    const float* gb1  = (const float*)d_in[10];
    const float* beb1 = (const float*)d_in[11];
    const float* Wb2  = (const float*)d_in[12];
    const float* bb2  = (const float*)d_in[13];

    float* hv_ws   = (float*)d_ws;                                   // 8192*128 f32 = 4 MB
    float* bias_ws = (float*)((char*)d_ws + (size_t)8192 * 128 * 4); // 8192*64  f32 = 2 MB

    hyper_kernel<<<Bq * Lq, 128, 0, stream>>>(z, W1, b1, g1, be1,
                                              Wb1, bb1, gb1, beb1, Wb2, bb2,
                                              hv_ws, bias_ws);

    dim3 grid(Lq / LT, Bq);  // (32, 32)
    fused_kernel<<<grid, 256, 0, stream>>>(x, W2, b2, hv_ws, bias_ws, (float*)d_out);
}

// Round 2
// 664.479 us; speedup vs baseline: 5.8626x; 5.8626x over previous
//
#include <hip/hip_runtime.h>

#define Bq  32
#define CIq 64
#define COq 64
#define Lq  256
#define Kq  3
#define Aq  16
#define Hq  128
#define EPSq 1e-5f

typedef short bf16x8 __attribute__((ext_vector_type(8)));
typedef float f32x4  __attribute__((ext_vector_type(4)));

__device__ __forceinline__ unsigned short f2bf(float f) {
    union { float f; unsigned u; } v; v.f = f;
    unsigned r = v.u + 0x7fffu + ((v.u >> 16) & 1u);
    return (unsigned short)(r >> 16);
}

// ---------------------------------------------------------------------------
// prep_w2: W2 fp32 [h=128][col=12288] -> W2r bf16 [c][h], c = o*192 + i*3 + k
// (original col = (i*64 + o)*3 + k). Also b2r[c] = b2[col] fp32.
// ---------------------------------------------------------------------------
__global__ __launch_bounds__(128) void prep_w2(
    const float* __restrict__ W2, const float* __restrict__ b2,
    unsigned short* __restrict__ W2r, float* __restrict__ b2r)
{
    const int c = blockIdx.x;       // 0..12287
    const int h = threadIdx.x;      // 0..127
    const int o = c / 192;
    const int rem = c - o * 192;
    const int i = rem / 3;
    const int k = rem - 3 * i;
    const int col = (i * COq + o) * 3 + k;
    W2r[(size_t)c * Hq + h] = f2bf(W2[(size_t)h * 12288 + col]);
    if (h == 0) b2r[c] = b2[col];
}

// ---------------------------------------------------------------------------
// hyper_kernel: per (b,l): hvb bf16[bl][128] = relu(LN(z@W1+b1)),
//               bias fp32[bl][64] = relu(LN(z@Wb1+bb1)) @ Wb2 + bb2
// ---------------------------------------------------------------------------
__global__ __launch_bounds__(128) void hyper_kernel(
    const float* __restrict__ z,
    const float* __restrict__ W1,  const float* __restrict__ b1,
    const float* __restrict__ g1,  const float* __restrict__ be1,
    const float* __restrict__ Wb1, const float* __restrict__ bb1,
    const float* __restrict__ gb1, const float* __restrict__ beb1,
    const float* __restrict__ Wb2, const float* __restrict__ bb2,
    unsigned short* __restrict__ hvb, float* __restrict__ bias_ws)
{
    const int bl = blockIdx.x;
    const int j  = threadIdx.x;

    __shared__ float zs[Aq];
    __shared__ float r1[Hq];
    __shared__ float r2[Hq];
    __shared__ float hbs[Hq];

    if (j < Aq) zs[j] = z[bl * Aq + j];
    __syncthreads();

    float pre = b1[j];
    #pragma unroll
    for (int a = 0; a < Aq; ++a) pre += zs[a] * W1[a * Hq + j];

    r1[j] = pre; r2[j] = pre * pre;
    __syncthreads();
    for (int off = 64; off > 0; off >>= 1) {
        if (j < off) { r1[j] += r1[j + off]; r2[j] += r2[j + off]; }
        __syncthreads();
    }
    float mu  = r1[0] * (1.0f / 128.0f);
    float var = r2[0] * (1.0f / 128.0f) - mu * mu;
    float hval = (pre - mu) * rsqrtf(var + EPSq) * g1[j] + be1[j];
    hval = hval > 0.0f ? hval : 0.0f;
    hvb[bl * Hq + j] = f2bf(hval);

    float preb = bb1[j];
    #pragma unroll
    for (int a = 0; a < Aq; ++a) preb += zs[a] * Wb1[a * Hq + j];

    __syncthreads();
    r1[j] = preb; r2[j] = preb * preb;
    __syncthreads();
    for (int off = 64; off > 0; off >>= 1) {
        if (j < off) { r1[j] += r1[j + off]; r2[j] += r2[j + off]; }
        __syncthreads();
    }
    float mub  = r1[0] * (1.0f / 128.0f);
    float varb = r2[0] * (1.0f / 128.0f) - mub * mub;
    float hbv = (preb - mub) * rsqrtf(varb + EPSq) * gb1[j] + beb1[j];
    hbv = hbv > 0.0f ? hbv : 0.0f;
    hbs[j] = hbv;
    __syncthreads();

    if (j < COq) {
        float acc = bb2[j];
        #pragma unroll 8
        for (int h = 0; h < Hq; ++h) acc += hbs[h] * Wb2[h * COq + j];
        bias_ws[bl * COq + j] = acc;
    }
}

// ---------------------------------------------------------------------------
// fused2: block = (b, l-tile of 8), 512 threads (8 waves).
// Per o-chunk (16 o's): GEMM1 (MFMA, M=16 pad, N=3072, K=128) -> wb LDS,
// then conv as per-tap MFMA C[s,o] += X[s,i] @ W[i,o], K=i=64.
// ---------------------------------------------------------------------------
__global__ __launch_bounds__(512, 2) void fused2(
    const float* __restrict__ x,
    const unsigned short* __restrict__ W2r, const float* __restrict__ b2r,
    const unsigned short* __restrict__ hvb, const float* __restrict__ bias_ws,
    float* __restrict__ out)
{
    const int b   = blockIdx.y;
    const int l0  = blockIdx.x * 8;
    const int tid = threadIdx.x;
    const int wv  = tid >> 6;
    const int lane = tid & 63;
    const int n    = lane & 15;
    const int quad = lane >> 4;

    // i-dim padded 64->72 (16B-aligned rows, 2-way-max bank pattern)
    __shared__ __align__(16) unsigned short xb[10 * 32 * 72];  // 46080 B [l'][s][i]
    __shared__ __align__(16) unsigned short wb[8 * 3 * 16 * 72]; // 55296 B [l][k][o][i]
    __shared__ __align__(16) float obuf[32 * 16 * 12];         // 24576 B [s][o][l pad12]
    __shared__ float bias_lds[8 * 64];                         // 2048 B

    bias_lds[tid & 511] = bias_ws[(size_t)(b * Lq + l0) * COq + (tid & 511)];

    // ---- stage x tile: xb[l'][s][i] = x[s,b,i,l0-1+l'] ----
    for (int v = tid; v < 32 * 64; v += 512) {
        int s = v >> 6, i = v & 63;
        const float* xp = x + (((size_t)s * Bq + b) * CIq + i) * Lq + (l0 - 1);
        #pragma unroll
        for (int q = 0; q < 10; ++q) {
            int ll = l0 - 1 + q;
            float val = (ll >= 0 && ll < Lq) ? xp[q] : 0.0f;
            xb[(q * 32 + s) * 72 + i] = f2bf(val);
        }
    }

    // ---- GEMM1 A-fragments (hv rows, pad rows 8..15 = 0), kept in regs ----
    bf16x8 ah[4];
    if (n < 8) {
        const unsigned short* hp = hvb + (size_t)(b * Lq + l0 + n) * Hq + quad * 8;
        #pragma unroll
        for (int ks = 0; ks < 4; ++ks) ah[ks] = *(const bf16x8*)(hp + ks * 32);
    } else {
        #pragma unroll
        for (int ks = 0; ks < 4; ++ks) ah[ks] = (bf16x8)0;
    }

    for (int oc = 0; oc < 4; ++oc) {
        __syncthreads();  // wb free (prev conv done); first iter: xb fill done

        // ---- GEMM1 for o-chunk: n-tiles t = wv + 8*m, processed in pairs ----
        for (int j = 0; j < 12; ++j) {
            const int t0 = wv + 16 * j;
            const int t1 = t0 + 8;
            const int cl0 = t0 * 16 + n;          // col-local in chunk, 0..3071
            const int cl1 = t1 * 16 + n;
            int ol0 = cl0 / 192, r0 = cl0 - ol0 * 192;
            int i0 = r0 / 3, k0 = r0 - 3 * i0;
            int ol1 = cl1 / 192, r1 = cl1 - ol1 * 192;
            int i1 = r1 / 3, k1 = r1 - 3 * i1;

            const unsigned short* bp0 = W2r + ((size_t)(oc * 3072 + cl0)) * Hq + quad * 8;
            const unsigned short* bp1 = W2r + ((size_t)(oc * 3072 + cl1)) * Hq + quad * 8;
            bf16x8 w00 = *(const bf16x8*)(bp0);
            bf16x8 w10 = *(const bf16x8*)(bp1);
            bf16x8 w01 = *(const bf16x8*)(bp0 + 32);
            bf16x8 w11 = *(const bf16x8*)(bp1 + 32);
            bf16x8 w02 = *(const bf16x8*)(bp0 + 64);
            bf16x8 w12 = *(const bf16x8*)(bp1 + 64);
            bf16x8 w03 = *(const bf16x8*)(bp0 + 96);
            bf16x8 w13 = *(const bf16x8*)(bp1 + 96);

            f32x4 a0 = {0.f, 0.f, 0.f, 0.f};
            f32x4 a1 = {0.f, 0.f, 0.f, 0.f};
            a0 = __builtin_amdgcn_mfma_f32_16x16x32_bf16(ah[0], w00, a0, 0, 0, 0);
            a1 = __builtin_amdgcn_mfma_f32_16x16x32_bf16(ah[0], w10, a1, 0, 0, 0);
            a0 = __builtin_amdgcn_mfma_f32_16x16x32_bf16(ah[1], w01, a0, 0, 0, 0);
            a1 = __builtin_amdgcn_mfma_f32_16x16x32_bf16(ah[1], w11, a1, 0, 0, 0);
            a0 = __builtin_amdgcn_mfma_f32_16x16x32_bf16(ah[2], w02, a0, 0, 0, 0);
            a1 = __builtin_amdgcn_mfma_f32_16x16x32_bf16(ah[2], w12, a1, 0, 0, 0);
            a0 = __builtin_amdgcn_mfma_f32_16x16x32_bf16(ah[3], w03, a0, 0, 0, 0);
            a1 = __builtin_amdgcn_mfma_f32_16x16x32_bf16(ah[3], w13, a1, 0, 0, 0);

            const float bv0 = b2r[oc * 3072 + cl0];
            const float bv1 = b2r[oc * 3072 + cl1];
            if (quad < 2) {
                #pragma unroll
                for (int r = 0; r < 4; ++r) {
                    int l = quad * 4 + r;   // rows 0..7 are the real l's
                    wb[((l * 3 + k0) * 16 + ol0) * 72 + i0] = f2bf(a0[r] + bv0);
                    wb[((l * 3 + k1) * 16 + ol1) * 72 + i1] = f2bf(a1[r] + bv1);
                }
            }
        }
        __syncthreads();  // wb ready

        // ---- conv: wave wv owns l = wv, both s m-tiles ----
        {
            const int l = wv;
            f32x4 c0 = {0.f, 0.f, 0.f, 0.f};
            f32x4 c1 = {0.f, 0.f, 0.f, 0.f};
            #pragma unroll
            for (int k = 0; k < Kq; ++k) {
                #pragma unroll
                for (int ks = 0; ks < 2; ++ks) {
                    bf16x8 bf = *(const bf16x8*)&wb[((l * 3 + k) * 16 + n) * 72 + ks * 32 + quad * 8];
                    bf16x8 xa0 = *(const bf16x8*)&xb[((l + k) * 32 + n) * 72 + ks * 32 + quad * 8];
                    bf16x8 xa1 = *(const bf16x8*)&xb[((l + k) * 32 + 16 + n) * 72 + ks * 32 + quad * 8];
                    c0 = __builtin_amdgcn_mfma_f32_16x16x32_bf16(xa0, bf, c0, 0, 0, 0);
                    c1 = __builtin_amdgcn_mfma_f32_16x16x32_bf16(xa1, bf, c1, 0, 0, 0);
                }
            }
            const float bv = bias_lds[l * COq + oc * 16 + n];
            #pragma unroll
            for (int r = 0; r < 4; ++r) {
                int s0 = quad * 4 + r;
                obuf[(s0 * 16 + n) * 12 + l]        = c0[r] + bv;
                obuf[((s0 + 16) * 16 + n) * 12 + l] = c1[r] + bv;
            }
        }
        __syncthreads();  // obuf ready

        // ---- drain obuf -> out, coalesced 32B per thread ----
        {
            const int s = tid >> 4, o = tid & 15;
            const float4* src = (const float4*)&obuf[(s * 16 + o) * 12];
            float4 v0 = src[0];
            float4 v1 = src[1];
            float* op = out + (((size_t)s * Bq + b) * COq + oc * 16 + o) * Lq + l0;
            *(float4*)op = v0;
            *(float4*)(op + 4) = v1;
        }
    }
}

// ---------------------------------------------------------------------------
extern "C" void kernel_launch(void* const* d_in, const int* in_sizes, int n_in,
                              void* d_out, int out_size, void* d_ws, size_t ws_size,
                              hipStream_t stream) {
    const float* x    = (const float*)d_in[0];
    const float* z    = (const float*)d_in[1];
    const float* W1   = (const float*)d_in[2];
    const float* b1   = (const float*)d_in[3];
    const float* g1   = (const float*)d_in[4];
    const float* be1  = (const float*)d_in[5];
    const float* W2   = (const float*)d_in[6];
    const float* b2   = (const float*)d_in[7];
    const float* Wb1  = (const float*)d_in[8];
    const float* bb1  = (const float*)d_in[9];
    const float* gb1  = (const float*)d_in[10];
    const float* beb1 = (const float*)d_in[11];
    const float* Wb2  = (const float*)d_in[12];
    const float* bb2  = (const float*)d_in[13];

    char* ws = (char*)d_ws;
    unsigned short* hvb     = (unsigned short*)(ws);                    // 2 MB
    float*          bias_ws = (float*)(ws + (size_t)2 * 1024 * 1024);   // 2 MB
    unsigned short* W2r     = (unsigned short*)(ws + (size_t)4 * 1024 * 1024); // 3 MB
    float*          b2r     = (float*)(ws + (size_t)7 * 1024 * 1024);   // 48 KB

    prep_w2<<<12288, 128, 0, stream>>>(W2, b2, W2r, b2r);
    hyper_kernel<<<Bq * Lq, 128, 0, stream>>>(z, W1, b1, g1, be1,
                                              Wb1, bb1, gb1, beb1, Wb2, bb2,
                                              hvb, bias_ws);

    dim3 grid(Lq / 8, Bq);  // (32, 32)
    fused2<<<grid, 512, 0, stream>>>(x, W2r, b2r, hvb, bias_ws, (float*)d_out);
}